// Round 13
// baseline (93.362 us; speedup 1.0000x reference)
//
#include <hip/hip_runtime.h>
#include <hip/hip_bf16.h>
#include <cstdint>

#define N_ROWS 4096
#define N_CLS  8192
#define D_EMB  512
#define K_DIM  1024   // bytes per row: [x^2 s-channel 512][2x ps-channel 512]

using f32x4 = __attribute__((ext_vector_type(4))) float;

__device__ __forceinline__ float softplus_f(float v) {
  return (v > 20.f) ? v : log1pf(expf(v));
}

// pack 2 f32 -> 2 fp8 e4m3 (OCP, RNE) in low 16 bits
__device__ __forceinline__ unsigned short pack2_e4m3(float a, float b) {
  return (unsigned short)(__builtin_amdgcn_cvt_pk_fp8_f32(a, b, 0, false) & 0xffff);
}

// block-wide sum for 256 threads (4 waves); re-entrant (syncs guard the LDS)
__device__ __forceinline__ float block_sum256(float v) {
  __shared__ float red[4];
  #pragma unroll
  for (int o = 32; o; o >>= 1) v += __shfl_xor(v, o);
  __syncthreads();
  if ((threadIdx.x & 63) == 0) red[threadIdx.x >> 6] = v;
  __syncthreads();
  return red[0] + red[1] + red[2] + red[3];
}

__device__ __forceinline__ void global_to_lds16(const void* g, void* l) {
  const __attribute__((address_space(1))) unsigned int* gp =
      reinterpret_cast<const __attribute__((address_space(1))) unsigned int*>(
          reinterpret_cast<uintptr_t>(g));
  __attribute__((address_space(3))) unsigned int* lp =
      reinterpret_cast<__attribute__((address_space(3))) unsigned int*>(
          reinterpret_cast<uintptr_t>(l));
  __builtin_amdgcn_global_load_lds(gp, lp, 16, 0, 0);
}

#define LGKM0() do { asm volatile("s_waitcnt lgkmcnt(0)" ::: "memory"); \
                     __builtin_amdgcn_sched_barrier(0); } while (0)

// ---------------------------------------------------------------------------
// K1: fused prep. Blocks [0, N_CLS): per-class -> Bmat fp8 [s | P*s], tvec,
//     klc. Blocks [N_CLS, N_CLS+N_ROWS): per-row -> Amat fp8 [-Xn^2 | 2Xn].
// ---------------------------------------------------------------------------
__global__ __launch_bounds__(256) void k_prep(const float* __restrict__ proxies,
                                              const float* __restrict__ sigmas_inv,
                                              const float* __restrict__ X,
                                              unsigned char* __restrict__ Bmat,
                                              unsigned char* __restrict__ Amat,
                                              float* __restrict__ tvec,
                                              float* __restrict__ klc) {
  const int bid = blockIdx.x;
  const int tid = threadIdx.x;
  if (bid < N_CLS) {
    const int c = bid;
    const float* p  = proxies    + (size_t)c * D_EMB;
    const float* si = sigmas_inv + (size_t)c * D_EMB;
    float2 p2 = ((const float2*)p)[tid];
    float ss = block_sum256(p2.x * p2.x + p2.y * p2.y);
    float invn = 1.0f / fmaxf(sqrtf(ss), 1e-12f);
    float2 s2 = ((const float2*)si)[tid];
    float sp0 = softplus_f(s2.x), sp1 = softplus_f(s2.y);
    float s0 = sp0 * sp0, s1 = sp1 * sp1;
    float pn0 = p2.x * invn, pn1 = p2.y * invn;
    float P0 = 3.0f * pn0, P1 = 3.0f * pn1;
    unsigned short* brow = (unsigned short*)(Bmat + (size_t)c * K_DIM);
    brow[tid]       = pack2_e4m3(s0, s1);
    brow[256 + tid] = pack2_e4m3(P0 * s0, P1 * s1);
    float tc = P0 * P0 * s0 + P1 * P1 * s1;
    float kl = 0.5f * (1.0f / s0 + pn0 * pn0 - 1.0f + 2.0f * logf(sp0))
             + 0.5f * (1.0f / s1 + pn1 * pn1 - 1.0f + 2.0f * logf(sp1));
    tc = block_sum256(tc);
    kl = block_sum256(kl);
    if (tid == 0) { tvec[c] = tc; klc[c] = kl; }
  } else {
    const int n = bid - N_CLS;
    const float* x = X + (size_t)n * D_EMB;
    float2 x2 = ((const float2*)x)[tid];
    float ss = block_sum256(x2.x * x2.x + x2.y * x2.y);
    float invn = 3.0f / fmaxf(sqrtf(ss), 1e-12f);   // SCALE folded in
    float v0 = x2.x * invn, v1 = x2.y * invn;
    unsigned short* arow = (unsigned short*)(Amat + (size_t)n * K_DIM);
    arow[tid]       = pack2_e4m3(-v0 * v0, -v1 * v1);
    arow[256 + tid] = pack2_e4m3(2.0f * v0, 2.0f * v1);
  }
}

// ---------------------------------------------------------------------------
// K3: 256x128-tile fp8 MFMA GEMM, R5 geometry (the measured tile optimum),
//     now with the full T3+T4 schedule — BOTH ingredients prior attempts
//     split: (a) fine 4-phase interleave {ds-read quadrant || stage-part ->
//     bar -> lgkm0 -> prio -> 8 MFMA -> bar} (R4 had this but drained vmcnt),
//     (b) counted vmcnt(3) across barriers via 3-slot LDS (R6 had this but
//     coarse phases). 8 waves = 4M x 2N, 64x64/wave; BK=64; 72 KB LDS
//     (2 blocks/CU). Fused LSE + target-logit epilogue (T hoisted as int4).
// ---------------------------------------------------------------------------
__global__ __launch_bounds__(512, 4) void k_gemm_lse(const unsigned char* __restrict__ Amat,
                                                     const unsigned char* __restrict__ Bmat,
                                                     const float* __restrict__ tvec,
                                                     const int* __restrict__ T,
                                                     float* __restrict__ Pm,
                                                     float* __restrict__ Psum,
                                                     float* __restrict__ tgt) {
  // slot s (24576 B): As[256][64] at s*24576 ; Bs[128][64] at s*24576+16384.
  // Epilogue ms[256][2][2] (4 KB) overlays slot 0 (all GEMM ds_reads are
  // lgkm-drained and barrier-ordered before the epilogue writes).
  __shared__ __align__(16) unsigned char lds[73728];
  const int tid  = threadIdx.x;
  const int lane = tid & 63;
  const int wave = tid >> 6;
  const int wr = wave >> 1, wc = wave & 1;          // 4x2 wave grid; 64x64/wave
  // T1: chunked XCD swizzle. nwg=1024, 128 consecutive per XCD.
  const int swz  = ((int)blockIdx.x & 7) * 128 + ((int)blockIdx.x >> 3);
  const int rt   = swz & 15;                        // 16 row tiles (256 rows)
  const int ct   = swz >> 4;                        // 64 col tiles (128 cols)
  const int row0 = rt * 256;
  const int col0 = ct * 128;

  f32x4 acc[4][4];
  #pragma unroll
  for (int i = 0; i < 4; ++i)
    #pragma unroll
    for (int j = 0; j < 4; ++j) acc[i][j] = (f32x4){0.f, 0.f, 0.f, 0.f};

  const int arow = wr * 64 + (lane & 15);           // + mi*16
  const int bcol = wc * 64 + (lane & 15);           // + ni*16
  const int kb8  = (lane >> 4) * 8;                 // k-byte within 32-chunk

  // ---- staging sources (R5 involution pattern, coalesced) ------------------
  const int f0  = tid * 16;
  const int sf0 = f0 ^ (((f0 >> 7) & 7) << 4);
  // sf(f0+8192) == sf0+8192 (bit 13 untouched by key bits 7-9).
  const unsigned char* gA0 = Amat + (size_t)(row0 + (sf0 >> 6)) * K_DIM + (sf0 & 63);
  const unsigned char* gB0 = Bmat + (size_t)(col0 + (sf0 >> 6)) * K_DIM + (sf0 & 63);

  auto stageA = [&](int slot, int ko) {             // 2 x 16B loads
    unsigned char* base = lds + slot * 24576;
    global_to_lds16(gA0 + ko,          base + f0);
    global_to_lds16(gA0 + 131072 + ko, base + 8192 + f0);   // rows 128..255
  };
  auto stageB = [&](int slot, int ko) {             // 1 x 16B load
    global_to_lds16(gB0 + ko, lds + slot * 24576 + 16384 + f0);
  };
  auto ld64 = [&](const unsigned char* base, int row, int kb) -> long {
    int f = row * 64 + kb;
    return *(const long*)(base + (f ^ (((f >> 7) & 7) << 4)));
  };

  // prologue: 2 tiles in flight; wait only for tile 0 (vmcnt(3) leaves
  // tile 1's 3 loads outstanding across the barrier).
  stageA(0, 0);  stageB(0, 0);
  stageA(1, 64); stageB(1, 64);
  asm volatile("s_waitcnt vmcnt(3)" ::: "memory");
  __builtin_amdgcn_sched_barrier(0);
  __builtin_amdgcn_s_barrier();

  long a01[4], a23[4], b01[4], b23[4];

#define GITER(T_, NW) { \
    const unsigned char* S  = lds + ((T_) % 3) * 24576; \
    const unsigned char* Sb = S + 16384; \
    /* P0: ds A(mi0-1)+B(ni0-1); stage-A(t+2); MFMA q(0,0) */ \
    a01[0] = ld64(S,  arow,      kb8); a01[1] = ld64(S,  arow,      32 + kb8); \
    a01[2] = ld64(S,  arow + 16, kb8); a01[3] = ld64(S,  arow + 16, 32 + kb8); \
    b01[0] = ld64(Sb, bcol,      kb8); b01[1] = ld64(Sb, bcol,      32 + kb8); \
    b01[2] = ld64(Sb, bcol + 16, kb8); b01[3] = ld64(Sb, bcol + 16, 32 + kb8); \
    if ((T_) + 2 < 16) stageA(((T_) + 2) % 3, ((T_) + 2) * 64); \
    __builtin_amdgcn_s_barrier(); \
    LGKM0(); \
    __builtin_amdgcn_s_setprio(1); \
    _Pragma("unroll") for (int mi = 0; mi < 2; ++mi) \
      _Pragma("unroll") for (int ni = 0; ni < 2; ++ni) \
        _Pragma("unroll") for (int ks = 0; ks < 2; ++ks) \
          acc[mi][ni] = __builtin_amdgcn_mfma_f32_16x16x32_fp8_fp8(a01[mi*2+ks], b01[ni*2+ks], acc[mi][ni], 0, 0, 0); \
    __builtin_amdgcn_s_setprio(0); \
    __builtin_amdgcn_s_barrier(); \
    /* P1: ds B(ni2-3); stage-B(t+2); MFMA q(0,1) */ \
    b23[0] = ld64(Sb, bcol + 32, kb8); b23[1] = ld64(Sb, bcol + 32, 32 + kb8); \
    b23[2] = ld64(Sb, bcol + 48, kb8); b23[3] = ld64(Sb, bcol + 48, 32 + kb8); \
    if ((T_) + 2 < 16) stageB(((T_) + 2) % 3, ((T_) + 2) * 64); \
    __builtin_amdgcn_s_barrier(); \
    LGKM0(); \
    __builtin_amdgcn_s_setprio(1); \
    _Pragma("unroll") for (int mi = 0; mi < 2; ++mi) \
      _Pragma("unroll") for (int ni = 0; ni < 2; ++ni) \
        _Pragma("unroll") for (int ks = 0; ks < 2; ++ks) \
          acc[mi][2+ni] = __builtin_amdgcn_mfma_f32_16x16x32_fp8_fp8(a01[mi*2+ks], b23[ni*2+ks], acc[mi][2+ni], 0, 0, 0); \
    __builtin_amdgcn_s_setprio(0); \
    __builtin_amdgcn_s_barrier(); \
    /* P2: ds A(mi2-3); MFMA q(1,1) */ \
    a23[0] = ld64(S, arow + 32, kb8); a23[1] = ld64(S, arow + 32, 32 + kb8); \
    a23[2] = ld64(S, arow + 48, kb8); a23[3] = ld64(S, arow + 48, 32 + kb8); \
    __builtin_amdgcn_s_barrier(); \
    LGKM0(); \
    __builtin_amdgcn_s_setprio(1); \
    _Pragma("unroll") for (int mi = 0; mi < 2; ++mi) \
      _Pragma("unroll") for (int ni = 0; ni < 2; ++ni) \
        _Pragma("unroll") for (int ks = 0; ks < 2; ++ks) \
          acc[2+mi][2+ni] = __builtin_amdgcn_mfma_f32_16x16x32_fp8_fp8(a23[mi*2+ks], b23[ni*2+ks], acc[2+mi][2+ni], 0, 0, 0); \
    __builtin_amdgcn_s_setprio(0); \
    __builtin_amdgcn_s_barrier(); \
    /* P3: MFMA q(1,0) on live regs; counted vmcnt (never 0 in steady state) */ \
    __builtin_amdgcn_s_setprio(1); \
    _Pragma("unroll") for (int mi = 0; mi < 2; ++mi) \
      _Pragma("unroll") for (int ni = 0; ni < 2; ++ni) \
        _Pragma("unroll") for (int ks = 0; ks < 2; ++ks) \
          acc[2+mi][ni] = __builtin_amdgcn_mfma_f32_16x16x32_fp8_fp8(a23[mi*2+ks], b01[ni*2+ks], acc[2+mi][ni], 0, 0, 0); \
    __builtin_amdgcn_s_setprio(0); \
    asm volatile("s_waitcnt vmcnt(" #NW ")" ::: "memory"); \
    __builtin_amdgcn_sched_barrier(0); \
    __builtin_amdgcn_s_barrier(); \
  }

  GITER(0, 3)  GITER(1, 3)  GITER(2, 3)  GITER(3, 3)
  GITER(4, 3)  GITER(5, 3)  GITER(6, 3)  GITER(7, 3)
  GITER(8, 3)  GITER(9, 3)  GITER(10, 3) GITER(11, 3)
  GITER(12, 3) GITER(13, 3) GITER(14, 0) GITER(15, 0)
#undef GITER

  // ---- epilogue: per-row max / sumexp + fused target logit.
  // C/D layout: col = lane&15, row = (lane>>4)*4 + j.
  float (*ms)[2][2] = (float (*)[2][2])lds;
  const int l15 = lane & 15;
  float tc[4];
  #pragma unroll
  for (int ni = 0; ni < 4; ++ni)
    tc[ni] = tvec[col0 + wc * 64 + ni * 16 + l15];
  const int cbase = col0 + wc * 64 + l15;           // + ni*16

  #pragma unroll
  for (int mi = 0; mi < 4; ++mi) {
    const int rowb = row0 + wr * 64 + mi * 16 + ((lane >> 4) << 2);
    int4 tv4 = *(const int4*)(T + rowb);
    int tvj[4] = {tv4.x, tv4.y, tv4.z, tv4.w};
    #pragma unroll
    for (int j = 0; j < 4; ++j) {
      const int d = tvj[j] - cbase;                 // match iff d == ni*16
      float z0 = acc[mi][0][j] - tc[0];
      float z1 = acc[mi][1][j] - tc[1];
      float z2 = acc[mi][2][j] - tc[2];
      float z3 = acc[mi][3][j] - tc[3];
      if (d == 0)  tgt[rowb + j] = z0;
      if (d == 16) tgt[rowb + j] = z1;
      if (d == 32) tgt[rowb + j] = z2;
      if (d == 48) tgt[rowb + j] = z3;
      float m = fmaxf(fmaxf(z0, z1), fmaxf(z2, z3));
      #pragma unroll
      for (int o = 1; o < 16; o <<= 1) m = fmaxf(m, __shfl_xor(m, o));
      float s = __expf(z0 - m) + __expf(z1 - m) + __expf(z2 - m) + __expf(z3 - m);
      #pragma unroll
      for (int o = 1; o < 16; o <<= 1) s += __shfl_xor(s, o);
      if (l15 == 0) {
        int rloc = wr * 64 + mi * 16 + ((lane >> 4) << 2) + j;
        ms[rloc][wc][0] = m;
        ms[rloc][wc][1] = s;
      }
    }
  }
  __syncthreads();
  if (tid < 256) {
    float m0 = ms[tid][0][0], s0 = ms[tid][0][1];
    float m1 = ms[tid][1][0], s1 = ms[tid][1][1];
    float M = fmaxf(m0, m1);
    float S = s0 * __expf(m0 - M) + s1 * __expf(m1 - M);
    Pm  [(size_t)(row0 + tid) * 64 + ct] = M;
    Psum[(size_t)(row0 + tid) * 64 + ct] = S;
  }
}

// ---------------------------------------------------------------------------
// K5a: 256-block LSE reduce. Block b: rows [b*16, b*16+16) -> ce partial
//      (16 lanes/row, 1 float4 each over 64 partials); classes
//      [b*32, b*32+32) -> kl partial.
// ---------------------------------------------------------------------------
__global__ __launch_bounds__(256) void k_red(const float* __restrict__ Pm,
                                             const float* __restrict__ Psum,
                                             const float* __restrict__ tgt,
                                             const float* __restrict__ klc,
                                             float* __restrict__ cep,
                                             float* __restrict__ klp) {
  const int b = blockIdx.x;
  const int tid = threadIdx.x;
  const int n = b * 16 + (tid >> 4);
  const int l4 = tid & 15;
  float4 pm = *(const float4*)(Pm   + (size_t)n * 64 + l4 * 4);
  float4 ps = *(const float4*)(Psum + (size_t)n * 64 + l4 * 4);
  float m = fmaxf(fmaxf(pm.x, pm.y), fmaxf(pm.z, pm.w));
  #pragma unroll
  for (int o = 1; o < 16; o <<= 1) m = fmaxf(m, __shfl_xor(m, o));
  float S = ps.x * __expf(pm.x - m) + ps.y * __expf(pm.y - m)
          + ps.z * __expf(pm.z - m) + ps.w * __expf(pm.w - m);
  #pragma unroll
  for (int o = 1; o < 16; o <<= 1) S += __shfl_xor(S, o);
  float ce = (l4 == 0) ? (m + logf(S) - tgt[n]) : 0.f;
  float kl = (tid < 32) ? klc[b * 32 + tid] : 0.f;
  ce = block_sum256(ce);
  kl = block_sum256(kl);
  if (tid == 0) { cep[b] = ce; klp[b] = kl; }
}

// K5b: final combine (1 block, 256 threads; 256 partials)
__global__ __launch_bounds__(256) void k_fin2(const float* __restrict__ cep,
                                              const float* __restrict__ klp,
                                              float* __restrict__ out) {
  const int tid = threadIdx.x;
  float ce = block_sum256(cep[tid]);
  float kl = block_sum256(klp[tid]);
  if (tid == 0) out[0] = ce / (float)N_ROWS + 0.2f * (kl / (float)N_CLS);
}

extern "C" void kernel_launch(void* const* d_in, const int* in_sizes, int n_in,
                              void* d_out, int out_size, void* d_ws, size_t ws_size,
                              hipStream_t stream) {
  const float* X          = (const float*)d_in[0];
  // d_in[1] = indices (unused by the reference loss)
  const int*   T          = (const int*)d_in[2];
  const float* proxies    = (const float*)d_in[3];
  const float* sigmas_inv = (const float*)d_in[4];

  char* ws = (char*)d_ws;
  unsigned char* Amat = (unsigned char*)ws;                            // 4 MiB
  unsigned char* Bmat = (unsigned char*)(ws + (4u << 20));             // 8 MiB
  float* tvec = (float*)(ws + (12u << 20));                            // 32 KiB
  float* klc  = (float*)(ws + (12u << 20) + (32u << 10));              // 32 KiB
  float* Pm   = (float*)(ws + (12u << 20) + (64u << 10));              // 1 MiB
  float* Psum = (float*)(ws + (13u << 20) + (64u << 10));              // 1 MiB
  float* tgt  = (float*)(ws + (14u << 20) + (64u << 10));              // 16 KiB
  float* cep  = (float*)(ws + (14u << 20) + (80u << 10));              // 1 KiB
  float* klp  = (float*)(ws + (14u << 20) + (84u << 10));              // 1 KiB
  float* out  = (float*)d_out;

  hipLaunchKernelGGL(k_prep,     dim3(N_CLS + N_ROWS), dim3(256), 0, stream,
                     proxies, sigmas_inv, X, Bmat, Amat, tvec, klc);
  hipLaunchKernelGGL(k_gemm_lse, dim3(1024),           dim3(512), 0, stream,
                     Amat, Bmat, tvec, T, Pm, Psum, tgt);
  hipLaunchKernelGGL(k_red,      dim3(256),            dim3(256), 0, stream,
                     Pm, Psum, tgt, klc, cep, klp);
  hipLaunchKernelGGL(k_fin2,     dim3(1),              dim3(256), 0, stream,
                     cep, klp, out);
}

// Round 14
// 88.718 us; speedup vs baseline: 1.0523x; 1.0523x over previous
//
#include <hip/hip_runtime.h>
#include <hip/hip_bf16.h>
#include <cstdint>

#define N_ROWS 4096
#define N_CLS  8192
#define D_EMB  512
#define K_DIM  1024   // bytes per row: [x^2 s-channel 512][2x ps-channel 512]

using f32x4 = __attribute__((ext_vector_type(4))) float;

__device__ __forceinline__ float softplus_f(float v) {
  return (v > 20.f) ? v : log1pf(expf(v));
}

// pack 2 f32 -> 2 fp8 e4m3 (OCP, RNE) in low 16 bits
__device__ __forceinline__ unsigned short pack2_e4m3(float a, float b) {
  return (unsigned short)(__builtin_amdgcn_cvt_pk_fp8_f32(a, b, 0, false) & 0xffff);
}

// block-wide sum for 256 threads (4 waves); re-entrant (syncs guard the LDS)
__device__ __forceinline__ float block_sum256(float v) {
  __shared__ float red[4];
  #pragma unroll
  for (int o = 32; o; o >>= 1) v += __shfl_xor(v, o);
  __syncthreads();
  if ((threadIdx.x & 63) == 0) red[threadIdx.x >> 6] = v;
  __syncthreads();
  return red[0] + red[1] + red[2] + red[3];
}

__device__ __forceinline__ void global_to_lds16(const void* g, void* l) {
  const __attribute__((address_space(1))) unsigned int* gp =
      reinterpret_cast<const __attribute__((address_space(1))) unsigned int*>(
          reinterpret_cast<uintptr_t>(g));
  __attribute__((address_space(3))) unsigned int* lp =
      reinterpret_cast<__attribute__((address_space(3))) unsigned int*>(
          reinterpret_cast<uintptr_t>(l));
  __builtin_amdgcn_global_load_lds(gp, lp, 16, 0, 0);
}

// ---------------------------------------------------------------------------
// K1: fused prep. Blocks [0, N_CLS): per-class -> Bmat fp8 [s | P*s], tvec,
//     klc. Blocks [N_CLS, N_CLS+N_ROWS): per-row -> Amat fp8 [-Xn^2 | 2Xn].
// ---------------------------------------------------------------------------
__global__ __launch_bounds__(256) void k_prep(const float* __restrict__ proxies,
                                              const float* __restrict__ sigmas_inv,
                                              const float* __restrict__ X,
                                              unsigned char* __restrict__ Bmat,
                                              unsigned char* __restrict__ Amat,
                                              float* __restrict__ tvec,
                                              float* __restrict__ klc) {
  const int bid = blockIdx.x;
  const int tid = threadIdx.x;
  if (bid < N_CLS) {
    const int c = bid;
    const float* p  = proxies    + (size_t)c * D_EMB;
    const float* si = sigmas_inv + (size_t)c * D_EMB;
    float2 p2 = ((const float2*)p)[tid];
    float ss = block_sum256(p2.x * p2.x + p2.y * p2.y);
    float invn = 1.0f / fmaxf(sqrtf(ss), 1e-12f);
    float2 s2 = ((const float2*)si)[tid];
    float sp0 = softplus_f(s2.x), sp1 = softplus_f(s2.y);
    float s0 = sp0 * sp0, s1 = sp1 * sp1;
    float pn0 = p2.x * invn, pn1 = p2.y * invn;
    float P0 = 3.0f * pn0, P1 = 3.0f * pn1;
    unsigned short* brow = (unsigned short*)(Bmat + (size_t)c * K_DIM);
    brow[tid]       = pack2_e4m3(s0, s1);
    brow[256 + tid] = pack2_e4m3(P0 * s0, P1 * s1);
    float tc = P0 * P0 * s0 + P1 * P1 * s1;
    float kl = 0.5f * (1.0f / s0 + pn0 * pn0 - 1.0f + 2.0f * logf(sp0))
             + 0.5f * (1.0f / s1 + pn1 * pn1 - 1.0f + 2.0f * logf(sp1));
    tc = block_sum256(tc);
    kl = block_sum256(kl);
    if (tid == 0) { tvec[c] = tc; klc[c] = kl; }
  } else {
    const int n = bid - N_CLS;
    const float* x = X + (size_t)n * D_EMB;
    float2 x2 = ((const float2*)x)[tid];
    float ss = block_sum256(x2.x * x2.x + x2.y * x2.y);
    float invn = 3.0f / fmaxf(sqrtf(ss), 1e-12f);   // SCALE folded in
    float v0 = x2.x * invn, v1 = x2.y * invn;
    unsigned short* arow = (unsigned short*)(Amat + (size_t)n * K_DIM);
    arow[tid]       = pack2_e4m3(-v0 * v0, -v1 * v1);
    arow[256 + tid] = pack2_e4m3(2.0f * v0, 2.0f * v1);
  }
}

// ---------------------------------------------------------------------------
// K3: R5-geometry 256x128-tile fp8 MFMA GEMM (measured optimum of tile scan
//     128^2/256x128/256^2 and of FIVE scheduling variants R4/R6/R7/R11/R13 —
//     all within +-8% of this simple 2-phase loop; the stall term is
//     wave-residency-bound latency, not schedule structure), with fused
//     target-logit extraction in the epilogue (same MFMA quantization as the
//     LSE logits -> errors cancel in ce). 8 waves = 4M x 2N, per-wave 64x64;
//     BK=64, 2-slot LDS (48 KB), stage-then-compute, XOR-involution swizzle,
//     setprio, XCD chunking.
// ---------------------------------------------------------------------------
__global__ __launch_bounds__(512, 4) void k_gemm_lse(const unsigned char* __restrict__ Amat,
                                                     const unsigned char* __restrict__ Bmat,
                                                     const float* __restrict__ tvec,
                                                     const int* __restrict__ T,
                                                     float* __restrict__ Pm,
                                                     float* __restrict__ Psum,
                                                     float* __restrict__ tgt) {
  union SMem {
    struct { unsigned char As[2][16384]; unsigned char Bs[2][8192]; } st; // 48 KB
    float ms[256][2][2];   // 4 KB epilogue combine (overlays As[0]; last tile reads slot 1)
  };
  __shared__ SMem sm;
  const int tid  = threadIdx.x;
  const int lane = tid & 63;
  const int wave = tid >> 6;
  const int wr = wave >> 1, wc = wave & 1;          // 4x2 wave grid; per-wave 64x64 out
  // T1: chunked XCD swizzle. nwg=1024, 128 consecutive per XCD.
  const int swz  = ((int)blockIdx.x & 7) * 128 + ((int)blockIdx.x >> 3);
  const int rt   = swz & 15;                        // 16 row tiles (256 rows)
  const int ct   = swz >> 4;                        // 64 col tiles (128 cols)
  const int row0 = rt * 256;
  const int col0 = ct * 128;

  f32x4 acc[4][4];
  #pragma unroll
  for (int i = 0; i < 4; ++i)
    #pragma unroll
    for (int j = 0; j < 4; ++j) acc[i][j] = (f32x4){0.f, 0.f, 0.f, 0.f};

  const int arow = wr * 64 + (lane & 15);           // + mi*16
  const int bcol = wc * 64 + (lane & 15);           // + ni*16
  const int kb8  = (lane >> 4) * 8;                 // k-byte within 32-chunk

  auto stage = [&](int buf, int ko) {
    #pragma unroll
    for (int rep = 0; rep < 2; ++rep) {             // A: 16 KB = 2 x (512*16B)
      int f  = rep * 8192 + tid * 16;
      int sf = f ^ (((f >> 7) & 7) << 4);
      global_to_lds16(Amat + (size_t)(row0 + (sf >> 6)) * K_DIM + ko + (sf & 63),
                      &sm.st.As[buf][f]);
    }
    {                                               // B: 8 KB = 1 x (512*16B)
      int f  = tid * 16;
      int sf = f ^ (((f >> 7) & 7) << 4);
      global_to_lds16(Bmat + (size_t)(col0 + (sf >> 6)) * K_DIM + ko + (sf & 63),
                      &sm.st.Bs[buf][f]);
    }
  };
  auto ld64 = [&](const unsigned char* base, int row, int kb) -> long {
    int f = row * 64 + kb;
    return *(const long*)(base + (f ^ (((f >> 7) & 7) << 4)));
  };

  stage(0, 0);
  __syncthreads();
  for (int t = 0; t < 16; ++t) {
    if (t < 15) stage((t + 1) & 1, (t + 1) * 64);   // issue next-tile loads FIRST
    const unsigned char* Ab = sm.st.As[t & 1];
    const unsigned char* Bb = sm.st.Bs[t & 1];
    __builtin_amdgcn_s_setprio(1);
    #pragma unroll
    for (int ks = 0; ks < 64; ks += 32) {
      long a[4], b[4];
      #pragma unroll
      for (int mi = 0; mi < 4; ++mi) a[mi] = ld64(Ab, arow + mi * 16, ks + kb8);
      #pragma unroll
      for (int ni = 0; ni < 4; ++ni) b[ni] = ld64(Bb, bcol + ni * 16, ks + kb8);
      #pragma unroll
      for (int mi = 0; mi < 4; ++mi)
        #pragma unroll
        for (int ni = 0; ni < 4; ++ni)
          acc[mi][ni] = __builtin_amdgcn_mfma_f32_16x16x32_fp8_fp8(a[mi], b[ni], acc[mi][ni], 0, 0, 0);
    }
    __builtin_amdgcn_s_setprio(0);
    __syncthreads();   // drains staging vmcnt AFTER compute: latency hidden
  }

  // ---- in-register epilogue: per-row max / sumexp over this wave's 64 cols,
  //      plus fused target-logit write. C/D layout: col=lane&15, row=(lane>>4)*4+j.
  const int l15 = lane & 15;
  float tc[4];
  #pragma unroll
  for (int ni = 0; ni < 4; ++ni)
    tc[ni] = tvec[col0 + wc * 64 + ni * 16 + l15];
  const int cbase = col0 + wc * 64 + l15;           // + ni*16

  #pragma unroll
  for (int mi = 0; mi < 4; ++mi) {
    #pragma unroll
    for (int j = 0; j < 4; ++j) {
      const int grow = row0 + wr * 64 + mi * 16 + ((lane >> 4) << 2) + j;
      const int d = T[grow] - cbase;                // match iff d == ni*16
      float z0 = acc[mi][0][j] - tc[0];
      float z1 = acc[mi][1][j] - tc[1];
      float z2 = acc[mi][2][j] - tc[2];
      float z3 = acc[mi][3][j] - tc[3];
      if (d == 0)  tgt[grow] = z0;
      if (d == 16) tgt[grow] = z1;
      if (d == 32) tgt[grow] = z2;
      if (d == 48) tgt[grow] = z3;
      float m = fmaxf(fmaxf(z0, z1), fmaxf(z2, z3));
      #pragma unroll
      for (int o = 1; o < 16; o <<= 1) m = fmaxf(m, __shfl_xor(m, o));
      float s = __expf(z0 - m) + __expf(z1 - m) + __expf(z2 - m) + __expf(z3 - m);
      #pragma unroll
      for (int o = 1; o < 16; o <<= 1) s += __shfl_xor(s, o);
      if (l15 == 0) {
        int rloc = wr * 64 + mi * 16 + ((lane >> 4) << 2) + j;
        sm.ms[rloc][wc][0] = m;
        sm.ms[rloc][wc][1] = s;
      }
    }
  }
  __syncthreads();
  if (tid < 256) {
    float m0 = sm.ms[tid][0][0], s0 = sm.ms[tid][0][1];
    float m1 = sm.ms[tid][1][0], s1 = sm.ms[tid][1][1];
    float M = fmaxf(m0, m1);
    float S = s0 * __expf(m0 - M) + s1 * __expf(m1 - M);
    Pm  [(size_t)(row0 + tid) * 64 + ct] = M;
    Psum[(size_t)(row0 + tid) * 64 + ct] = S;
  }
}

// ---------------------------------------------------------------------------
// K5a: 256-block LSE reduce (target dot comes from the GEMM epilogue).
//      Block b: rows [b*16, b*16+16) -> ce partial (16 lanes/row, 1 float4
//      each over 64 partials); classes [b*32, b*32+32) -> kl partial.
// ---------------------------------------------------------------------------
__global__ __launch_bounds__(256) void k_red(const float* __restrict__ Pm,
                                             const float* __restrict__ Psum,
                                             const float* __restrict__ tgt,
                                             const float* __restrict__ klc,
                                             float* __restrict__ cep,
                                             float* __restrict__ klp) {
  const int b = blockIdx.x;
  const int tid = threadIdx.x;
  const int n = b * 16 + (tid >> 4);
  const int l4 = tid & 15;
  float4 pm = *(const float4*)(Pm   + (size_t)n * 64 + l4 * 4);
  float4 ps = *(const float4*)(Psum + (size_t)n * 64 + l4 * 4);
  float m = fmaxf(fmaxf(pm.x, pm.y), fmaxf(pm.z, pm.w));
  #pragma unroll
  for (int o = 1; o < 16; o <<= 1) m = fmaxf(m, __shfl_xor(m, o));
  float S = ps.x * __expf(pm.x - m) + ps.y * __expf(pm.y - m)
          + ps.z * __expf(pm.z - m) + ps.w * __expf(pm.w - m);
  #pragma unroll
  for (int o = 1; o < 16; o <<= 1) S += __shfl_xor(S, o);
  float ce = (l4 == 0) ? (m + logf(S) - tgt[n]) : 0.f;
  float kl = (tid < 32) ? klc[b * 32 + tid] : 0.f;
  ce = block_sum256(ce);
  kl = block_sum256(kl);
  if (tid == 0) { cep[b] = ce; klp[b] = kl; }
}

// K5b: final combine (1 block, 256 threads; 256 partials)
__global__ __launch_bounds__(256) void k_fin2(const float* __restrict__ cep,
                                              const float* __restrict__ klp,
                                              float* __restrict__ out) {
  const int tid = threadIdx.x;
  float ce = block_sum256(cep[tid]);
  float kl = block_sum256(klp[tid]);
  if (tid == 0) out[0] = ce / (float)N_ROWS + 0.2f * (kl / (float)N_CLS);
}

extern "C" void kernel_launch(void* const* d_in, const int* in_sizes, int n_in,
                              void* d_out, int out_size, void* d_ws, size_t ws_size,
                              hipStream_t stream) {
  const float* X          = (const float*)d_in[0];
  // d_in[1] = indices (unused by the reference loss)
  const int*   T          = (const int*)d_in[2];
  const float* proxies    = (const float*)d_in[3];
  const float* sigmas_inv = (const float*)d_in[4];

  char* ws = (char*)d_ws;
  unsigned char* Amat = (unsigned char*)ws;                            // 4 MiB
  unsigned char* Bmat = (unsigned char*)(ws + (4u << 20));             // 8 MiB
  float* tvec = (float*)(ws + (12u << 20));                            // 32 KiB
  float* klc  = (float*)(ws + (12u << 20) + (32u << 10));              // 32 KiB
  float* Pm   = (float*)(ws + (12u << 20) + (64u << 10));              // 1 MiB
  float* Psum = (float*)(ws + (13u << 20) + (64u << 10));              // 1 MiB
  float* tgt  = (float*)(ws + (14u << 20) + (64u << 10));              // 16 KiB
  float* cep  = (float*)(ws + (14u << 20) + (80u << 10));              // 1 KiB
  float* klp  = (float*)(ws + (14u << 20) + (84u << 10));              // 1 KiB
  float* out  = (float*)d_out;

  hipLaunchKernelGGL(k_prep,     dim3(N_CLS + N_ROWS), dim3(256), 0, stream,
                     proxies, sigmas_inv, X, Bmat, Amat, tvec, klc);
  hipLaunchKernelGGL(k_gemm_lse, dim3(1024),           dim3(512), 0, stream,
                     Amat, Bmat, tvec, T, Pm, Psum, tgt);
  hipLaunchKernelGGL(k_red,      dim3(256),            dim3(256), 0, stream,
                     Pm, Psum, tgt, klc, cep, klp);
  hipLaunchKernelGGL(k_fin2,     dim3(1),              dim3(256), 0, stream,
                     cep, klp, out);
}